// Round 6
// baseline (388.482 us; speedup 1.0000x reference)
//
#include <hip/hip_runtime.h>
#include <hip/hip_bf16.h>
#include <stdint.h>

#define B_    256
#define T_    32
#define V_    10000
#define E_    512
#define H_    512
#define NSTEP 31
#define M_    7936      // NSTEP*B_
#define NG_   2048      // 4*H_
#define VPAD_ 10240
#define SENTU 0x7FC07FC0u   // 2x bf16 NaN sentinel (|h|<1 can never produce it)

typedef __attribute__((ext_vector_type(8))) short  short8;
typedef __attribute__((ext_vector_type(4))) float  f32x4;

static __device__ __forceinline__ unsigned short f2bf(float f) {
  __hip_bfloat16 h = __float2bfloat16(f);
  return *reinterpret_cast<unsigned short*>(&h);
}
static __device__ __forceinline__ ushort4 f4_to_bf4(float4 a) {
  ushort4 r; r.x = f2bf(a.x); r.y = f2bf(a.y); r.z = f2bf(a.z); r.w = f2bf(a.w); return r;
}
// fast gate math: __expf -> v_exp_f32; sigmoid never NaNs (1/(1+inf)=0);
// tanh clamped so exp(-2x) stays finite.
static __device__ __forceinline__ float fsig(float x) {
  return 1.f / (1.f + __expf(-x));
}
static __device__ __forceinline__ float ftanh_(float x) {
  x = fminf(fmaxf(x, -30.f), 30.f);
  float e = __expf(-2.f * x);
  return (1.f - e) / (1.f + e);
}

#define GLOAD_LDS16(gp, lp)                                                                   \
  __builtin_amdgcn_global_load_lds((const __attribute__((address_space(1))) unsigned int*)(gp), \
                                   (__attribute__((address_space(3))) unsigned int*)(lp), 16, 0, 0)

// Coherence-point (bypass L1+L2) access helpers — no cache-maintenance needed.
static __device__ __forceinline__ void store8_cc(void* p, uint2 v) {
  asm volatile("global_store_dwordx2 %0, %1, off sc0 sc1" :: "v"(p), "v"(v) : "memory");
}
static __device__ __forceinline__ uint4 load16_cc(const void* p) {
  uint4 r;
  asm volatile("global_load_dwordx4 %0, %1, off sc0 sc1" : "=v"(r) : "v"(p) : "memory");
  return r;
}

// -------------------------------------------------- weights fp32 -> bf16, bias
__global__ __launch_bounds__(256) void k_prep(
    const float* __restrict__ Wih, const float* __restrict__ Whh,
    const float* __restrict__ Wlin, const float* __restrict__ bih,
    const float* __restrict__ bhh,
    unsigned short* __restrict__ Wihb, unsigned short* __restrict__ Whhb,
    unsigned short* __restrict__ Wlb, float* __restrict__ bias) {
  const int stride = gridDim.x * 256;
  const int i0 = blockIdx.x * 256 + threadIdx.x;
  for (int q = i0; q < (NG_ * E_) / 4; q += stride) {
    ((ushort4*)Wihb)[q] = f4_to_bf4(((const float4*)Wih)[q]);
    ((ushort4*)Whhb)[q] = f4_to_bf4(((const float4*)Whh)[q]);
  }
  for (int q = i0; q < (VPAD_ * H_) / 4; q += stride) {
    int row = q >> 7;  // 128 quads per 512-elem row
    ushort4 r;
    if (row < V_) r = f4_to_bf4(((const float4*)Wlin)[q]);
    else { r.x = 0; r.y = 0; r.z = 0; r.w = 0; }
    ((ushort4*)Wlb)[q] = r;
  }
  for (int q = i0; q < NG_; q += stride) bias[q] = bih[q] + bhh[q];
}

// --- embedding gather -> bf16 X, h0 -> HsAll[0], sentinel-fill HsAll[1..31],
// --- zero out[0]
__global__ __launch_bounds__(256) void k_gather(
    const int* __restrict__ caps, const float* __restrict__ embed,
    const float* __restrict__ latent,
    unsigned short* __restrict__ Xbf, unsigned short* __restrict__ HsAll,
    float* __restrict__ out0) {
  const int stride = gridDim.x * 256;
  const int i0 = blockIdx.x * 256 + threadIdx.x;
  for (int q = i0; q < (M_ * E_) / 4; q += stride) {
    int m = q >> 7;          // row (t*256+b)
    int e4 = q & 127;
    int t = m >> 8, b = m & 255;
    int tok = caps[b * T_ + t];
    float4 a = ((const float4*)(embed + (size_t)tok * E_))[e4];
    ((ushort4*)Xbf)[q] = f4_to_bf4(a);
  }
  for (int q = i0; q < (B_ * H_) / 4; q += stride)
    ((ushort4*)HsAll)[q] = f4_to_bf4(((const float4*)latent)[q]);
  // sentinel-fill slots 1..31 (re-done every call: graph replays don't re-poison)
  uint4 s4 = make_uint4(SENTU, SENTU, SENTU, SENTU);
  uint4* hs1 = (uint4*)(HsAll + (size_t)B_ * H_);
  for (int q = i0; q < (NSTEP * B_ * H_) / 8; q += stride)
    hs1[q] = s4;
  float4 z = make_float4(0.f, 0.f, 0.f, 0.f);
  for (int q = i0; q < (B_ * V_) / 4; q += stride)
    ((float4*)out0)[q] = z;
}

// ------------------------------------------------------------ 128x128 bf16 GEMM
// A [M,512] bf16 row-major, Bt [N,512] bf16 row-major (i.e. op(B)=B^T),
// Out fp32 [M, ldo], out = A*Bt^T + bias (cols >= Nvalid discarded).
// XCD-aware bijective block swizzle when nwg % 8 == 0.
__global__ __launch_bounds__(256) void gemm128(
    const unsigned short* __restrict__ A, const unsigned short* __restrict__ Bt,
    const float* __restrict__ bias, float* __restrict__ Out, int ldo, int Nvalid) {
  __shared__ unsigned short As[128 * 32];
  __shared__ unsigned short Bs[128 * 32];
  const int tid = threadIdx.x;
  const int w = tid >> 6, l = tid & 63;
  const int wr = w >> 1, wc = w & 1;

  int flat = blockIdx.y * gridDim.x + blockIdx.x;
  int nwg = gridDim.x * gridDim.y;
  int tile = flat;
  if ((nwg & 7) == 0) { int cpx = nwg >> 3; tile = (flat & 7) * cpx + (flat >> 3); }
  const int bm = tile / gridDim.x, bn = tile % gridDim.x;

  const int srow = (w << 4) + (l >> 2);   // staging row 0..63
  const int skof = (l & 3) << 3;          // k offset in elems
  const unsigned short* ag0 = A + (size_t)(bm * 128 + srow) * 512 + skof;
  const unsigned short* ag1 = ag0 + (size_t)64 * 512;
  const unsigned short* bg0 = Bt + (size_t)(bn * 128 + srow) * 512 + skof;
  const unsigned short* bg1 = bg0 + (size_t)64 * 512;
  unsigned short* al0 = As + ((w << 4)) * 32;
  unsigned short* al1 = As + (64 + (w << 4)) * 32;
  unsigned short* bl0 = Bs + ((w << 4)) * 32;
  unsigned short* bl1 = Bs + (64 + (w << 4)) * 32;

  f32x4 acc[4][4] = {};
  const int lr = l & 15;
  const int lk = (l >> 4) << 3;

  for (int kk = 0; kk < 16; ++kk) {
    const int ko = kk << 5;
    GLOAD_LDS16(ag0 + ko, al0);
    GLOAD_LDS16(ag1 + ko, al1);
    GLOAD_LDS16(bg0 + ko, bl0);
    GLOAD_LDS16(bg1 + ko, bl1);
    __syncthreads();
    short8 af[4], bf8[4];
#pragma unroll
    for (int m = 0; m < 4; ++m)
      af[m] = *(const short8*)(As + (wr * 64 + m * 16 + lr) * 32 + lk);
#pragma unroll
    for (int n = 0; n < 4; ++n)
      bf8[n] = *(const short8*)(Bs + (wc * 64 + n * 16 + lr) * 32 + lk);
#pragma unroll
    for (int m = 0; m < 4; ++m)
#pragma unroll
      for (int n = 0; n < 4; ++n)
        acc[m][n] = __builtin_amdgcn_mfma_f32_16x16x32_bf16(af[m], bf8[n], acc[m][n], 0, 0, 0);
    __syncthreads();
  }

  const int orow0 = bm * 128 + wr * 64 + ((l >> 4) << 2);
  const int ocol0 = bn * 128 + wc * 64 + lr;
#pragma unroll
  for (int n = 0; n < 4; ++n) {
    int col = ocol0 + n * 16;
    if (col < Nvalid) {
      float bb = bias[col];
#pragma unroll
      for (int m = 0; m < 4; ++m) {
        int row = orow0 + m * 16;
#pragma unroll
        for (int r = 0; r < 4; ++r)
          Out[(size_t)(row + r) * ldo + col] = acc[m][n][r] + bb;
      }
    }
  }
}

// ---------------------------- persistent LSTM chain (sentinel-synced, flag-free)
// 128 blocks x 256 threads. Block = 32 batch rows x 32 h-cols, fixed for all 31
// steps. Wave w = gate group w. Whh fragments live in registers; c in registers.
// h ping-pongs through HsAll (slot t = h_{t-1}).
// Sync: the DATA is the flag. HsAll slots 1..31 are pre-filled with bf16-NaN
// sentinel 0x7FC0 (unreachable: |h| = |sigmoid*tanh| < 1). Producers fire
// sc0|sc1 stores and move on (no drain, no fence, no flag). Consumers reload
// their 32KB h-tile from the coherence point until no uint == 0x7FC07FC0
// (4B single-copy atomicity + 8B-aligned stores => no tearing).
// Correct for ANY block->XCD placement (G16). Co-residency via coop launch.
__global__ __launch_bounds__(256, 1) void k_chain(
    const float* __restrict__ Xg,             // [31][256][2048] x@Wih^T + bias
    const unsigned short* __restrict__ Whhb,  // [2048][512] bf16
    unsigned short* __restrict__ HsAll) {     // [32][256][512] bf16; slot0 = h0
  __shared__ unsigned short hsh[32 * 512];    // 32 KB, XOR-swizzled chunks
  __shared__ float gsh[4][32 * 32];           // 16 KB
  const int tid = threadIdx.x;
  const int w = tid >> 6, l = tid & 63;
  const int gb = blockIdx.x & 7;              // batch group 0..7 (XCD-local heuristic)
  const int b0 = gb << 5;
  const int n0 = (blockIdx.x >> 3) << 5;      // col tile 0..15
  const int lr = l & 15;
  const int lk = (l >> 4) << 3;

  // ---- preload Whh fragments for this block's tile (gate group w, cols n0..n0+31)
  short8 bf0[16], bf1[16];
  {
    const unsigned short* wb0 = Whhb + (size_t)(w * 512 + n0 + lr) * 512 + lk;
    const unsigned short* wb1 = wb0 + (size_t)16 * 512;
#pragma unroll 16
    for (int ks = 0; ks < 16; ++ks) {
      bf0[ks] = *(const short8*)(wb0 + (ks << 5));
      bf1[ks] = *(const short8*)(wb1 + (ks << 5));
    }
  }
  float c_reg[4] = {0.f, 0.f, 0.f, 0.f};

  // cell ownership for the update phase: row br, 4 consecutive cols nc0
  const int br = tid >> 3;
  const int nc0 = (tid & 7) << 2;
  const size_t xg_base = ((size_t)(b0 + br) << 11) + n0 + nc0;

  for (int t = 0; t < NSTEP; ++t) {
    // ---- prefetch this step's Xg gate values into registers (cached loads;
    // latency hides under the sentinel-retry staging)
    const f32x4* xp = (const f32x4*)(Xg + (size_t)t * B_ * NG_ + xg_base);
    f32x4 xiv = xp[0];          // gate i  (+0)
    f32x4 xfv = xp[128];        // gate f  (+512 floats)
    f32x4 xgv = xp[256];        // gate g  (+1024)
    f32x4 xov = xp[384];        // gate o  (+1536)

    // ---- stage h_{t-1} rows b0..b0+31: retry until sentinel-free (data=flag)
    const unsigned short* h_in = HsAll + (size_t)t * B_ * H_;
    uint4 hreg[8];
    int ok;
    do {
#pragma unroll
      for (int j = 0; j < 8; ++j) {
        int row = (j << 2) + w;
        hreg[j] = load16_cc(h_in + (size_t)(b0 + row) * 512 + (l << 3));
      }
      asm volatile("s_waitcnt vmcnt(0)" ::: "memory");
      __builtin_amdgcn_sched_barrier(0);   // keep compares below the wait
      int val = 1;
#pragma unroll
      for (int j = 0; j < 8; ++j) {
        val &= (hreg[j].x != SENTU);
        val &= (hreg[j].y != SENTU);
        val &= (hreg[j].z != SENTU);
        val &= (hreg[j].w != SENTU);
      }
      ok = __syncthreads_and(val);
      if (!ok) __builtin_amdgcn_s_sleep(2);
    } while (!ok);

    // XOR-swizzled LDS write (chunk c of row lands at chunk c^(row&7))
#pragma unroll
    for (int j = 0; j < 8; ++j) {
      int row = (j << 2) + w;
      *(uint4*)(hsh + row * 512 + ((l ^ (row & 7)) << 3)) = hreg[j];
    }
    __syncthreads();

    // ---- h @ Whh^T for this gate group / col tile
    f32x4 acc[2][2] = {};
#pragma unroll
    for (int ks = 0; ks < 16; ++ks) {
      int kc = (ks << 2) + (l >> 4);
      short8 a0 = *(const short8*)(hsh + lr * 512 + ((kc ^ (lr & 7)) << 3));
      short8 a1 = *(const short8*)(hsh + (16 + lr) * 512 + ((kc ^ (lr & 7)) << 3));
      acc[0][0] = __builtin_amdgcn_mfma_f32_16x16x32_bf16(a0, bf0[ks], acc[0][0], 0, 0, 0);
      acc[0][1] = __builtin_amdgcn_mfma_f32_16x16x32_bf16(a0, bf1[ks], acc[0][1], 0, 0, 0);
      acc[1][0] = __builtin_amdgcn_mfma_f32_16x16x32_bf16(a1, bf0[ks], acc[1][0], 0, 0, 0);
      acc[1][1] = __builtin_amdgcn_mfma_f32_16x16x32_bf16(a1, bf1[ks], acc[1][1], 0, 0, 0);
    }

    // ---- gate tiles -> LDS (gate groups live in different waves)
    const int gr0 = (l >> 4) << 2;
#pragma unroll
    for (int m = 0; m < 2; ++m)
#pragma unroll
      for (int n = 0; n < 2; ++n)
#pragma unroll
        for (int r = 0; r < 4; ++r)
          gsh[w][(m * 16 + gr0 + r) * 32 + n * 16 + lr] = acc[m][n][r];
    __syncthreads();

    // ---- cell update + h_out (4 consecutive cells per thread, fast math)
    f32x4 giv = *(const f32x4*)&gsh[0][(br << 5) + nc0];
    f32x4 gfv = *(const f32x4*)&gsh[1][(br << 5) + nc0];
    f32x4 ggv = *(const f32x4*)&gsh[2][(br << 5) + nc0];
    f32x4 gov = *(const f32x4*)&gsh[3][(br << 5) + nc0];
    ushort4 hv;
    unsigned short* hvp = &hv.x;
#pragma unroll
    for (int j = 0; j < 4; ++j) {
      float is = fsig(giv[j] + xiv[j]);
      float fs = fsig(gfv[j] + xfv[j]);
      float os = fsig(gov[j] + xov[j]);
      float gt = ftanh_(ggv[j] + xgv[j]);
      float cn = fs * c_reg[j] + is * gt;
      c_reg[j] = cn;
      hvp[j] = f2bf(os * ftanh_(cn));
    }
    unsigned short* h_out = HsAll + (size_t)(t + 1) * B_ * H_;
    store8_cc(h_out + ((size_t)(b0 + br) << 9) + n0 + nc0,
              *reinterpret_cast<uint2*>(&hv));
    // no drain, no fence, no flag: consumers detect via the data itself.
  }
}

extern "C" void kernel_launch(void* const* d_in, const int* in_sizes, int n_in,
                              void* d_out, int out_size, void* d_ws, size_t ws_size,
                              hipStream_t stream) {
  const int*   caps   = (const int*)d_in[0];
  const float* latent = (const float*)d_in[1];
  const float* embed  = (const float*)d_in[2];
  const float* Wih    = (const float*)d_in[3];
  const float* Whh    = (const float*)d_in[4];
  const float* bih    = (const float*)d_in[5];
  const float* bhh    = (const float*)d_in[6];
  const float* Wlin   = (const float*)d_in[7];
  const float* blin   = (const float*)d_in[8];
  float* out = (float*)d_out;

  char* ws = (char*)d_ws;
  size_t off = 0;
  auto alloc = [&](size_t bytes) {
    void* p = ws + off;
    off = (off + bytes + 255) & ~(size_t)255;
    return p;
  };
  unsigned short* Xbf   = (unsigned short*)alloc((size_t)M_ * E_ * 2);
  unsigned short* Wihb  = (unsigned short*)alloc((size_t)NG_ * E_ * 2);
  unsigned short* Whhb  = (unsigned short*)alloc((size_t)NG_ * H_ * 2);
  unsigned short* Wlb   = (unsigned short*)alloc((size_t)VPAD_ * H_ * 2);
  float*          bias  = (float*)alloc((size_t)NG_ * 4);
  float*          Xg    = (float*)alloc((size_t)M_ * NG_ * 4);
  unsigned short* HsAll = (unsigned short*)alloc((size_t)(NSTEP + 1) * B_ * H_ * 2);
  (void)ws_size; (void)in_sizes; (void)n_in; (void)out_size;

  hipLaunchKernelGGL(k_prep, dim3(2048), dim3(256), 0, stream,
                     Wih, Whh, Wlin, bih, bhh, Wihb, Whhb, Wlb, bias);
  hipLaunchKernelGGL(k_gather, dim3(2048), dim3(256), 0, stream,
                     caps, embed, latent, Xbf, HsAll, out);
  // Xg = X @ Wih^T + bias   [7936 x 2048]
  hipLaunchKernelGGL(gemm128, dim3(NG_ / 128, M_ / 128), dim3(256), 0, stream,
                     Xbf, Wihb, bias, Xg, NG_, NG_);
  // persistent LSTM chain, sentinel-synced (cooperative launch only for
  // guaranteed co-residency of all 128 blocks)
  {
    const float* XgC = Xg;
    const unsigned short* WhhC = Whhb;
    unsigned short* HsC = HsAll;
    void* args[] = {(void*)&XgC, (void*)&WhhC, (void*)&HsC};
    hipLaunchCooperativeKernel((const void*)k_chain, dim3(128), dim3(256),
                               args, 0, stream);
  }
  // logits = Hs @ Wlin^T + b_lin  -> out rows starting at B_*V_
  hipLaunchKernelGGL(gemm128, dim3(VPAD_ / 128, M_ / 128), dim3(256), 0, stream,
                     HsAll + (size_t)B_ * H_, Wlb, blin, out + (size_t)B_ * V_, V_, V_);
}

// Round 7
// 378.911 us; speedup vs baseline: 1.0253x; 1.0253x over previous
//
#include <hip/hip_runtime.h>
#include <hip/hip_bf16.h>
#include <stdint.h>

#define B_    256
#define T_    32
#define V_    10000
#define E_    512
#define H_    512
#define NSTEP 31
#define M_    7936      // NSTEP*B_
#define NG_   2048      // 4*H_
#define VPAD_ 10240
#define SENTU 0x7FC07FC0u   // 2x bf16 NaN sentinel (|h|<1 can never produce it)

typedef __attribute__((ext_vector_type(8))) short  short8;
typedef __attribute__((ext_vector_type(4))) float  f32x4;

static __device__ __forceinline__ unsigned short f2bf(float f) {
  __hip_bfloat16 h = __float2bfloat16(f);
  return *reinterpret_cast<unsigned short*>(&h);
}
static __device__ __forceinline__ ushort4 f4_to_bf4(float4 a) {
  ushort4 r; r.x = f2bf(a.x); r.y = f2bf(a.y); r.z = f2bf(a.z); r.w = f2bf(a.w); return r;
}
// fast gate math: __expf -> v_exp_f32; sigmoid never NaNs (1/(1+inf)=0);
// tanh clamped so exp(-2x) stays finite.
static __device__ __forceinline__ float fsig(float x) {
  return 1.f / (1.f + __expf(-x));
}
static __device__ __forceinline__ float ftanh_(float x) {
  x = fminf(fmaxf(x, -30.f), 30.f);
  float e = __expf(-2.f * x);
  return (1.f - e) / (1.f + e);
}

#define GLOAD_LDS16(gp, lp)                                                                   \
  __builtin_amdgcn_global_load_lds((const __attribute__((address_space(1))) unsigned int*)(gp), \
                                   (__attribute__((address_space(3))) unsigned int*)(lp), 16, 0, 0)

// Coherence-point (bypass L1+L2) access helpers — no cache-maintenance needed.
static __device__ __forceinline__ void store8_cc(void* p, uint2 v) {
  asm volatile("global_store_dwordx2 %0, %1, off sc0 sc1" :: "v"(p), "v"(v) : "memory");
}
static __device__ __forceinline__ uint4 load16_cc(const void* p) {
  uint4 r;
  asm volatile("global_load_dwordx4 %0, %1, off sc0 sc1" : "=v"(r) : "v"(p) : "memory");
  return r;
}

// -------------------------------------------------- weights fp32 -> bf16, bias
__global__ __launch_bounds__(256) void k_prep(
    const float* __restrict__ Wih, const float* __restrict__ Whh,
    const float* __restrict__ Wlin, const float* __restrict__ bih,
    const float* __restrict__ bhh,
    unsigned short* __restrict__ Wihb, unsigned short* __restrict__ Whhb,
    unsigned short* __restrict__ Wlb, float* __restrict__ bias) {
  const int stride = gridDim.x * 256;
  const int i0 = blockIdx.x * 256 + threadIdx.x;
  for (int q = i0; q < (NG_ * E_) / 4; q += stride) {
    ((ushort4*)Wihb)[q] = f4_to_bf4(((const float4*)Wih)[q]);
    ((ushort4*)Whhb)[q] = f4_to_bf4(((const float4*)Whh)[q]);
  }
  for (int q = i0; q < (VPAD_ * H_) / 4; q += stride) {
    int row = q >> 7;  // 128 quads per 512-elem row
    ushort4 r;
    if (row < V_) r = f4_to_bf4(((const float4*)Wlin)[q]);
    else { r.x = 0; r.y = 0; r.z = 0; r.w = 0; }
    ((ushort4*)Wlb)[q] = r;
  }
  for (int q = i0; q < NG_; q += stride) bias[q] = bih[q] + bhh[q];
}

// --- embedding gather -> bf16 X, h0 -> HsAll[0], sentinel-fill HsAll[1..31],
// --- zero out[0]
__global__ __launch_bounds__(256) void k_gather(
    const int* __restrict__ caps, const float* __restrict__ embed,
    const float* __restrict__ latent,
    unsigned short* __restrict__ Xbf, unsigned short* __restrict__ HsAll,
    float* __restrict__ out0) {
  const int stride = gridDim.x * 256;
  const int i0 = blockIdx.x * 256 + threadIdx.x;
  for (int q = i0; q < (M_ * E_) / 4; q += stride) {
    int m = q >> 7;          // row (t*256+b)
    int e4 = q & 127;
    int t = m >> 8, b = m & 255;
    int tok = caps[b * T_ + t];
    float4 a = ((const float4*)(embed + (size_t)tok * E_))[e4];
    ((ushort4*)Xbf)[q] = f4_to_bf4(a);
  }
  for (int q = i0; q < (B_ * H_) / 4; q += stride)
    ((ushort4*)HsAll)[q] = f4_to_bf4(((const float4*)latent)[q]);
  // sentinel-fill slots 1..31 (re-done every call: graph replays don't re-poison)
  uint4 s4 = make_uint4(SENTU, SENTU, SENTU, SENTU);
  uint4* hs1 = (uint4*)(HsAll + (size_t)B_ * H_);
  for (int q = i0; q < (NSTEP * B_ * H_) / 8; q += stride)
    hs1[q] = s4;
  float4 z = make_float4(0.f, 0.f, 0.f, 0.f);
  for (int q = i0; q < (B_ * V_) / 4; q += stride)
    ((float4*)out0)[q] = z;
}

// ---------------------------------------------------- 256x256 bf16 GEMM, BK=64
// A [M,512] bf16 rm, Bt [N,512] bf16 rm (op(B)=B^T), Out fp32 [M,ldo] =
// A*Bt^T + bias. 512 threads = 8 waves (2 wr x 4 wc), per-wave out 128x64.
// Double-buffered LDS (2x 256x64 per matrix = 128 KB): prefetch K-tile t+1
// with global_load_lds BEFORE computing K-tile t; one vmcnt(0)+barrier per
// K-step (T3-minimum 2-phase). Epilogue uses NON-TEMPORAL stores so the fp32
// output stream doesn't evict A/B panels from L2/L3 (round-6 FETCH diagnosis).
__global__ __launch_bounds__(512, 2) void gemm256(
    const unsigned short* __restrict__ A, const unsigned short* __restrict__ Bt,
    const float* __restrict__ bias, float* __restrict__ Out, int ldo, int Nvalid) {
  __shared__ unsigned short As[2 * 256 * 64];   // 64 KB
  __shared__ unsigned short Bs[2 * 256 * 64];   // 64 KB
  const int tid = threadIdx.x;
  const int w = tid >> 6, l = tid & 63;
  const int wr = w >> 2, wc = w & 3;

  int flat = blockIdx.y * gridDim.x + blockIdx.x;
  int nwg = gridDim.x * gridDim.y;
  int tile = flat;
  if ((nwg & 7) == 0) { int cpx = nwg >> 3; tile = (flat & 7) * cpx + (flat >> 3); }
  const int bm = tile / gridDim.x, bn = tile % gridDim.x;

  // staging: issue i covers rows i*64..i*64+63; wave w rows +w*8, lane l>>3;
  // lane l&7 -> col chunk (l&7)*8. LDS dest = wave-uniform base + lane*16B.
  const unsigned short* Ab = A + (size_t)(bm * 256 + (w << 3) + (l >> 3)) * 512 + ((l & 7) << 3);
  const unsigned short* Bb = Bt + (size_t)(bn * 256 + (w << 3) + (l >> 3)) * 512 + ((l & 7) << 3);
  unsigned short* Al = As + (w << 9);   // + i*4096 + buf*16384
  unsigned short* Bl = Bs + (w << 9);

  f32x4 acc[8][4] = {};
  const int lr = l & 15;
  const int lk = (l >> 4) << 3;

  // prologue: stage K-tile 0 into buffer 0
#pragma unroll
  for (int i = 0; i < 4; ++i) {
    GLOAD_LDS16(Ab + (size_t)(i << 6) * 512, Al + (i << 12));
    GLOAD_LDS16(Bb + (size_t)(i << 6) * 512, Bl + (i << 12));
  }
  asm volatile("s_waitcnt vmcnt(0)" ::: "memory");
  __syncthreads();

  for (int t = 0; t < 8; ++t) {
    const int cur = (t & 1) << 14;
    if (t < 7) {
      const int nb = ((t & 1) ^ 1) << 14;
      const int k0 = (t + 1) << 6;
#pragma unroll
      for (int i = 0; i < 4; ++i) {
        GLOAD_LDS16(Ab + (size_t)(i << 6) * 512 + k0, Al + nb + (i << 12));
        GLOAD_LDS16(Bb + (size_t)(i << 6) * 512 + k0, Bl + nb + (i << 12));
      }
    }
    const unsigned short* ab = As + cur;
    const unsigned short* bb = Bs + cur;
#pragma unroll
    for (int kc = 0; kc < 2; ++kc) {
      short8 af[8], bf8[4];
#pragma unroll
      for (int m = 0; m < 8; ++m)
        af[m] = *(const short8*)(ab + ((wr << 7) + (m << 4) + lr) * 64 + (kc << 5) + lk);
#pragma unroll
      for (int n = 0; n < 4; ++n)
        bf8[n] = *(const short8*)(bb + ((wc << 6) + (n << 4) + lr) * 64 + (kc << 5) + lk);
#pragma unroll
      for (int m = 0; m < 8; ++m)
#pragma unroll
        for (int n = 0; n < 4; ++n)
          acc[m][n] = __builtin_amdgcn_mfma_f32_16x16x32_bf16(af[m], bf8[n], acc[m][n], 0, 0, 0);
    }
    asm volatile("s_waitcnt vmcnt(0)" ::: "memory");
    __syncthreads();
  }

  const int orow0 = bm * 256 + (wr << 7) + ((l >> 4) << 2);
  const int ocol0 = bn * 256 + (wc << 6) + lr;
#pragma unroll
  for (int n = 0; n < 4; ++n) {
    int col = ocol0 + (n << 4);
    if (col < Nvalid) {
      float bv = bias[col];
#pragma unroll
      for (int m = 0; m < 8; ++m) {
        int row = orow0 + (m << 4);
#pragma unroll
        for (int r = 0; r < 4; ++r)
          __builtin_nontemporal_store(acc[m][n][r] + bv,
                                      &Out[(size_t)(row + r) * ldo + col]);
      }
    }
  }
}

// ---------------------------- persistent LSTM chain (sentinel-synced, flag-free)
// 128 blocks x 256 threads. Block = 32 batch rows x 32 h-cols, fixed for all 31
// steps. Wave w = gate group w. Whh fragments live in registers; c in registers.
// h ping-pongs through HsAll (slot t = h_{t-1}).
// Sync: the DATA is the flag. HsAll slots 1..31 are pre-filled with bf16-NaN
// sentinel 0x7FC0 (unreachable: |h| = |sigmoid*tanh| < 1). Producers fire
// sc0|sc1 stores and move on. Consumers reload their 32KB h-tile from the
// coherence point until no uint == 0x7FC07FC0.
__global__ __launch_bounds__(256, 1) void k_chain(
    const float* __restrict__ Xg,             // [31][256][2048] x@Wih^T + bias
    const unsigned short* __restrict__ Whhb,  // [2048][512] bf16
    unsigned short* __restrict__ HsAll) {     // [32][256][512] bf16; slot0 = h0
  __shared__ unsigned short hsh[32 * 512];    // 32 KB, XOR-swizzled chunks
  __shared__ float gsh[4][32 * 32];           // 16 KB
  const int tid = threadIdx.x;
  const int w = tid >> 6, l = tid & 63;
  const int gb = blockIdx.x & 7;              // batch group 0..7 (XCD-local heuristic)
  const int b0 = gb << 5;
  const int n0 = (blockIdx.x >> 3) << 5;      // col tile 0..15
  const int lr = l & 15;
  const int lk = (l >> 4) << 3;

  // ---- preload Whh fragments for this block's tile (gate group w, cols n0..n0+31)
  short8 bf0[16], bf1[16];
  {
    const unsigned short* wb0 = Whhb + (size_t)(w * 512 + n0 + lr) * 512 + lk;
    const unsigned short* wb1 = wb0 + (size_t)16 * 512;
#pragma unroll 16
    for (int ks = 0; ks < 16; ++ks) {
      bf0[ks] = *(const short8*)(wb0 + (ks << 5));
      bf1[ks] = *(const short8*)(wb1 + (ks << 5));
    }
  }
  float c_reg[4] = {0.f, 0.f, 0.f, 0.f};

  // cell ownership for the update phase: row br, 4 consecutive cols nc0
  const int br = tid >> 3;
  const int nc0 = (tid & 7) << 2;
  const size_t xg_base = ((size_t)(b0 + br) << 11) + n0 + nc0;

  for (int t = 0; t < NSTEP; ++t) {
    // ---- prefetch this step's Xg gate values into registers (cached loads;
    // latency hides under the sentinel-retry staging)
    const f32x4* xp = (const f32x4*)(Xg + (size_t)t * B_ * NG_ + xg_base);
    f32x4 xiv = xp[0];          // gate i  (+0)
    f32x4 xfv = xp[128];        // gate f  (+512 floats)
    f32x4 xgv = xp[256];        // gate g  (+1024)
    f32x4 xov = xp[384];        // gate o  (+1536)

    // ---- stage h_{t-1} rows b0..b0+31: retry until sentinel-free (data=flag)
    const unsigned short* h_in = HsAll + (size_t)t * B_ * H_;
    uint4 hreg[8];
    int ok;
    do {
#pragma unroll
      for (int j = 0; j < 8; ++j) {
        int row = (j << 2) + w;
        hreg[j] = load16_cc(h_in + (size_t)(b0 + row) * 512 + (l << 3));
      }
      asm volatile("s_waitcnt vmcnt(0)" ::: "memory");
      __builtin_amdgcn_sched_barrier(0);   // keep compares below the wait
      int val = 1;
#pragma unroll
      for (int j = 0; j < 8; ++j) {
        val &= (hreg[j].x != SENTU);
        val &= (hreg[j].y != SENTU);
        val &= (hreg[j].z != SENTU);
        val &= (hreg[j].w != SENTU);
      }
      ok = __syncthreads_and(val);
      if (!ok) __builtin_amdgcn_s_sleep(2);
    } while (!ok);

    // XOR-swizzled LDS write (chunk c of row lands at chunk c^(row&7))
#pragma unroll
    for (int j = 0; j < 8; ++j) {
      int row = (j << 2) + w;
      *(uint4*)(hsh + row * 512 + ((l ^ (row & 7)) << 3)) = hreg[j];
    }
    __syncthreads();

    // ---- h @ Whh^T for this gate group / col tile
    f32x4 acc[2][2] = {};
#pragma unroll
    for (int ks = 0; ks < 16; ++ks) {
      int kc = (ks << 2) + (l >> 4);
      short8 a0 = *(const short8*)(hsh + lr * 512 + ((kc ^ (lr & 7)) << 3));
      short8 a1 = *(const short8*)(hsh + (16 + lr) * 512 + ((kc ^ (lr & 7)) << 3));
      acc[0][0] = __builtin_amdgcn_mfma_f32_16x16x32_bf16(a0, bf0[ks], acc[0][0], 0, 0, 0);
      acc[0][1] = __builtin_amdgcn_mfma_f32_16x16x32_bf16(a0, bf1[ks], acc[0][1], 0, 0, 0);
      acc[1][0] = __builtin_amdgcn_mfma_f32_16x16x32_bf16(a1, bf0[ks], acc[1][0], 0, 0, 0);
      acc[1][1] = __builtin_amdgcn_mfma_f32_16x16x32_bf16(a1, bf1[ks], acc[1][1], 0, 0, 0);
    }

    // ---- gate tiles -> LDS (gate groups live in different waves)
    const int gr0 = (l >> 4) << 2;
#pragma unroll
    for (int m = 0; m < 2; ++m)
#pragma unroll
      for (int n = 0; n < 2; ++n)
#pragma unroll
        for (int r = 0; r < 4; ++r)
          gsh[w][(m * 16 + gr0 + r) * 32 + n * 16 + lr] = acc[m][n][r];
    __syncthreads();

    // ---- cell update + h_out (4 consecutive cells per thread, fast math)
    f32x4 giv = *(const f32x4*)&gsh[0][(br << 5) + nc0];
    f32x4 gfv = *(const f32x4*)&gsh[1][(br << 5) + nc0];
    f32x4 ggv = *(const f32x4*)&gsh[2][(br << 5) + nc0];
    f32x4 gov = *(const f32x4*)&gsh[3][(br << 5) + nc0];
    ushort4 hv;
    unsigned short* hvp = &hv.x;
#pragma unroll
    for (int j = 0; j < 4; ++j) {
      float is = fsig(giv[j] + xiv[j]);
      float fs = fsig(gfv[j] + xfv[j]);
      float os = fsig(gov[j] + xov[j]);
      float gt = ftanh_(ggv[j] + xgv[j]);
      float cn = fs * c_reg[j] + is * gt;
      c_reg[j] = cn;
      hvp[j] = f2bf(os * ftanh_(cn));
    }
    unsigned short* h_out = HsAll + (size_t)(t + 1) * B_ * H_;
    store8_cc(h_out + ((size_t)(b0 + br) << 9) + n0 + nc0,
              *reinterpret_cast<uint2*>(&hv));
    // no drain, no fence, no flag: consumers detect via the data itself.
  }
}

extern "C" void kernel_launch(void* const* d_in, const int* in_sizes, int n_in,
                              void* d_out, int out_size, void* d_ws, size_t ws_size,
                              hipStream_t stream) {
  const int*   caps   = (const int*)d_in[0];
  const float* latent = (const float*)d_in[1];
  const float* embed  = (const float*)d_in[2];
  const float* Wih    = (const float*)d_in[3];
  const float* Whh    = (const float*)d_in[4];
  const float* bih    = (const float*)d_in[5];
  const float* bhh    = (const float*)d_in[6];
  const float* Wlin   = (const float*)d_in[7];
  const float* blin   = (const float*)d_in[8];
  float* out = (float*)d_out;

  char* ws = (char*)d_ws;
  size_t off = 0;
  auto alloc = [&](size_t bytes) {
    void* p = ws + off;
    off = (off + bytes + 255) & ~(size_t)255;
    return p;
  };
  unsigned short* Xbf   = (unsigned short*)alloc((size_t)M_ * E_ * 2);
  unsigned short* Wihb  = (unsigned short*)alloc((size_t)NG_ * E_ * 2);
  unsigned short* Whhb  = (unsigned short*)alloc((size_t)NG_ * H_ * 2);
  unsigned short* Wlb   = (unsigned short*)alloc((size_t)VPAD_ * H_ * 2);
  float*          bias  = (float*)alloc((size_t)NG_ * 4);
  float*          Xg    = (float*)alloc((size_t)M_ * NG_ * 4);
  unsigned short* HsAll = (unsigned short*)alloc((size_t)(NSTEP + 1) * B_ * H_ * 2);
  (void)ws_size; (void)in_sizes; (void)n_in; (void)out_size;

  hipLaunchKernelGGL(k_prep, dim3(2048), dim3(256), 0, stream,
                     Wih, Whh, Wlin, bih, bhh, Wihb, Whhb, Wlb, bias);
  hipLaunchKernelGGL(k_gather, dim3(2048), dim3(256), 0, stream,
                     caps, embed, latent, Xbf, HsAll, out);
  // Xg = X @ Wih^T + bias   [7936 x 2048]
  hipLaunchKernelGGL(gemm256, dim3(NG_ / 256, M_ / 256), dim3(512), 0, stream,
                     Xbf, Wihb, bias, Xg, NG_, NG_);
  // persistent LSTM chain, sentinel-synced (cooperative launch only for
  // guaranteed co-residency of all 128 blocks)
  {
    const float* XgC = Xg;
    const unsigned short* WhhC = Whhb;
    unsigned short* HsC = HsAll;
    void* args[] = {(void*)&XgC, (void*)&WhhC, (void*)&HsC};
    hipLaunchCooperativeKernel((const void*)k_chain, dim3(128), dim3(256),
                               args, 0, stream);
  }
  // logits = Hs @ Wlin^T + b_lin  -> out rows starting at B_*V_
  hipLaunchKernelGGL(gemm256, dim3(VPAD_ / 256, M_ / 256), dim3(512), 0, stream,
                     HsAll + (size_t)B_ * H_, Wlb, blin, out + (size_t)B_ * V_, V_, V_);
}

// Round 8
// 361.298 us; speedup vs baseline: 1.0752x; 1.0488x over previous
//
#include <hip/hip_runtime.h>
#include <hip/hip_bf16.h>
#include <stdint.h>

#define B_    256
#define T_    32
#define V_    10000
#define E_    512
#define H_    512
#define NSTEP 31
#define M_    7936      // NSTEP*B_
#define NG_   2048      // 4*H_
#define VPAD_ 10240
#define SENTU 0x7FC07FC0u   // 2x bf16 NaN sentinel (|h|<1 can never produce it)

typedef __attribute__((ext_vector_type(8))) short  short8;
typedef __attribute__((ext_vector_type(4))) float  f32x4;

static __device__ __forceinline__ unsigned short f2bf(float f) {
  __hip_bfloat16 h = __float2bfloat16(f);
  return *reinterpret_cast<unsigned short*>(&h);
}
static __device__ __forceinline__ ushort4 f4_to_bf4(float4 a) {
  ushort4 r; r.x = f2bf(a.x); r.y = f2bf(a.y); r.z = f2bf(a.z); r.w = f2bf(a.w); return r;
}
// fast gate math: __expf -> v_exp_f32; sigmoid never NaNs (1/(1+inf)=0);
// tanh clamped so exp(-2x) stays finite.
static __device__ __forceinline__ float fsig(float x) {
  return 1.f / (1.f + __expf(-x));
}
static __device__ __forceinline__ float ftanh_(float x) {
  x = fminf(fmaxf(x, -30.f), 30.f);
  float e = __expf(-2.f * x);
  return (1.f - e) / (1.f + e);
}

#define GLOAD_LDS16(gp, lp)                                                                   \
  __builtin_amdgcn_global_load_lds((const __attribute__((address_space(1))) unsigned int*)(gp), \
                                   (__attribute__((address_space(3))) unsigned int*)(lp), 16, 0, 0)

// Coherence-point (bypass L1+L2) access helpers — no cache-maintenance needed.
static __device__ __forceinline__ void store8_cc(void* p, uint2 v) {
  asm volatile("global_store_dwordx2 %0, %1, off sc0 sc1" :: "v"(p), "v"(v) : "memory");
}
static __device__ __forceinline__ uint4 load16_cc(const void* p) {
  uint4 r;
  asm volatile("global_load_dwordx4 %0, %1, off sc0 sc1" : "=v"(r) : "v"(p) : "memory");
  return r;
}

// -------------------------------------------------- weights fp32 -> bf16, bias
__global__ __launch_bounds__(256) void k_prep(
    const float* __restrict__ Wih, const float* __restrict__ Whh,
    const float* __restrict__ Wlin, const float* __restrict__ bih,
    const float* __restrict__ bhh,
    unsigned short* __restrict__ Wihb, unsigned short* __restrict__ Whhb,
    unsigned short* __restrict__ Wlb, float* __restrict__ bias) {
  const int stride = gridDim.x * 256;
  const int i0 = blockIdx.x * 256 + threadIdx.x;
  for (int q = i0; q < (NG_ * E_) / 4; q += stride) {
    ((ushort4*)Wihb)[q] = f4_to_bf4(((const float4*)Wih)[q]);
    ((ushort4*)Whhb)[q] = f4_to_bf4(((const float4*)Whh)[q]);
  }
  for (int q = i0; q < (VPAD_ * H_) / 4; q += stride) {
    int row = q >> 7;  // 128 quads per 512-elem row
    ushort4 r;
    if (row < V_) r = f4_to_bf4(((const float4*)Wlin)[q]);
    else { r.x = 0; r.y = 0; r.z = 0; r.w = 0; }
    ((ushort4*)Wlb)[q] = r;
  }
  for (int q = i0; q < NG_; q += stride) bias[q] = bih[q] + bhh[q];
}

// --- embedding gather -> bf16 X, h0 -> HsAll[0], sentinel-fill HsAll[1..31],
// --- zero out[0]
__global__ __launch_bounds__(256) void k_gather(
    const int* __restrict__ caps, const float* __restrict__ embed,
    const float* __restrict__ latent,
    unsigned short* __restrict__ Xbf, unsigned short* __restrict__ HsAll,
    float* __restrict__ out0) {
  const int stride = gridDim.x * 256;
  const int i0 = blockIdx.x * 256 + threadIdx.x;
  for (int q = i0; q < (M_ * E_) / 4; q += stride) {
    int m = q >> 7;          // row (t*256+b)
    int e4 = q & 127;
    int t = m >> 8, b = m & 255;
    int tok = caps[b * T_ + t];
    float4 a = ((const float4*)(embed + (size_t)tok * E_))[e4];
    ((ushort4*)Xbf)[q] = f4_to_bf4(a);
  }
  for (int q = i0; q < (B_ * H_) / 4; q += stride)
    ((ushort4*)HsAll)[q] = f4_to_bf4(((const float4*)latent)[q]);
  // sentinel-fill slots 1..31 (re-done every call: graph replays don't re-poison)
  uint4 s4 = make_uint4(SENTU, SENTU, SENTU, SENTU);
  uint4* hs1 = (uint4*)(HsAll + (size_t)B_ * H_);
  for (int q = i0; q < (NSTEP * B_ * H_) / 8; q += stride)
    hs1[q] = s4;
  float4 z = make_float4(0.f, 0.f, 0.f, 0.f);
  for (int q = i0; q < (B_ * V_) / 4; q += stride)
    ((float4*)out0)[q] = z;
}

// ---------------------------------------------------- 256x256 bf16 GEMM, BK=64
// A [M,512] bf16 rm, Bt [N,512] bf16 rm (op(B)=B^T), Out fp32 [M,ldo] =
// A*Bt^T + bias. 512 threads = 8 waves (2 wr x 4 wc), per-wave out 128x64.
// Double-buffered LDS; prefetch K-tile t+1 BEFORE computing K-tile t; one
// vmcnt(0)+barrier per K-step.
// LDS layout is XOR-swizzled (both-sides, rule 21): LDS chunk q (16B) of row r
// holds GLOBAL chunk q^(r&7). global_load_lds dest stays linear; the global
// SOURCE address is pre-swizzled at staging; ds_reads apply the same XOR.
// Kills the 16-way bank conflict of the linear 128B-stride layout.
// NT: non-temporal epilogue stores (output never re-read; protects L2/L3).
template<bool NT>
__global__ __launch_bounds__(512, 2) void gemm256(
    const unsigned short* __restrict__ A, const unsigned short* __restrict__ Bt,
    const float* __restrict__ bias, float* __restrict__ Out, int ldo, int Nvalid) {
  __shared__ unsigned short As[2 * 256 * 64];   // 64 KB
  __shared__ unsigned short Bs[2 * 256 * 64];   // 64 KB
  const int tid = threadIdx.x;
  const int w = tid >> 6, l = tid & 63;
  const int wr = w >> 2, wc = w & 3;

  int flat = blockIdx.y * gridDim.x + blockIdx.x;
  int nwg = gridDim.x * gridDim.y;
  int tile = flat;
  if ((nwg & 7) == 0) { int cpx = nwg >> 3; tile = (flat & 7) * cpx + (flat >> 3); }
  const int bm = tile / gridDim.x, bn = tile % gridDim.x;

  // staging: issue i covers rows i*64..i*64+63; wave w rows +w*8, lane l>>3;
  // lane l writes LDS chunk (l&7) of row; global source chunk = (l&7)^(l>>3)
  // so that LDS chunk q holds global chunk q^(row&7).
  const int srow = (w << 3) + (l >> 3);
  const int schunk = (l & 7) ^ ((l >> 3) & 7);
  const unsigned short* Ab = A + (size_t)(bm * 256 + srow) * 512 + (schunk << 3);
  const unsigned short* Bb = Bt + (size_t)(bn * 256 + srow) * 512 + (schunk << 3);
  unsigned short* Al = As + (w << 9);   // + i*4096 + buf*16384 (linear dest)
  unsigned short* Bl = Bs + (w << 9);

  f32x4 acc[8][4] = {};
  const int lr = l & 15;

  // prologue: stage K-tile 0 into buffer 0
#pragma unroll
  for (int i = 0; i < 4; ++i) {
    GLOAD_LDS16(Ab + (size_t)(i << 6) * 512, Al + (i << 12));
    GLOAD_LDS16(Bb + (size_t)(i << 6) * 512, Bl + (i << 12));
  }
  asm volatile("s_waitcnt vmcnt(0)" ::: "memory");
  __syncthreads();

  for (int t = 0; t < 8; ++t) {
    const int cur = (t & 1) << 14;
    if (t < 7) {
      const int nb = ((t & 1) ^ 1) << 14;
      const int k0 = (t + 1) << 6;
#pragma unroll
      for (int i = 0; i < 4; ++i) {
        GLOAD_LDS16(Ab + (size_t)(i << 6) * 512 + k0, Al + nb + (i << 12));
        GLOAD_LDS16(Bb + (size_t)(i << 6) * 512 + k0, Bl + nb + (i << 12));
      }
    }
    const unsigned short* ab = As + cur;
    const unsigned short* bb = Bs + cur;
#pragma unroll
    for (int kc = 0; kc < 2; ++kc) {
      const int cI = (kc << 2) + (l >> 4);        // chunk index 0..7
      const int rchunk = (cI ^ (lr & 7)) << 3;    // swizzled read offset (elems)
      short8 af[8], bf8[4];
#pragma unroll
      for (int m = 0; m < 8; ++m)
        af[m] = *(const short8*)(ab + ((wr << 7) + (m << 4) + lr) * 64 + rchunk);
#pragma unroll
      for (int n = 0; n < 4; ++n)
        bf8[n] = *(const short8*)(bb + ((wc << 6) + (n << 4) + lr) * 64 + rchunk);
#pragma unroll
      for (int m = 0; m < 8; ++m)
#pragma unroll
        for (int n = 0; n < 4; ++n)
          acc[m][n] = __builtin_amdgcn_mfma_f32_16x16x32_bf16(af[m], bf8[n], acc[m][n], 0, 0, 0);
    }
    asm volatile("s_waitcnt vmcnt(0)" ::: "memory");
    __syncthreads();
  }

  const int orow0 = bm * 256 + (wr << 7) + ((l >> 4) << 2);
  const int ocol0 = bn * 256 + (wc << 6) + lr;
#pragma unroll
  for (int n = 0; n < 4; ++n) {
    int col = ocol0 + (n << 4);
    if (col < Nvalid) {
      float bv = bias[col];
#pragma unroll
      for (int m = 0; m < 8; ++m) {
        int row = orow0 + (m << 4);
#pragma unroll
        for (int r = 0; r < 4; ++r) {
          float v = acc[m][n][r] + bv;
          float* p = &Out[(size_t)(row + r) * ldo + col];
          if (NT) __builtin_nontemporal_store(v, p);
          else    *p = v;
        }
      }
    }
  }
}

// ---------------------------- persistent LSTM chain (sentinel-synced, flag-free)
// 128 blocks x 256 threads. Block = 32 batch rows x 32 h-cols, fixed for all 31
// steps. Wave w = gate group w. Whh fragments live in registers; c in registers.
// h ping-pongs through HsAll (slot t = h_{t-1}).
// Sync: the DATA is the flag. HsAll slots 1..31 are pre-filled with bf16-NaN
// sentinel 0x7FC0 (unreachable: |h| = |sigmoid*tanh| < 1). Producers fire
// sc0|sc1 stores and move on. Consumers reload their 32KB h-tile from the
// coherence point until no uint == 0x7FC07FC0.
__global__ __launch_bounds__(256, 1) void k_chain(
    const float* __restrict__ Xg,             // [31][256][2048] x@Wih^T + bias
    const unsigned short* __restrict__ Whhb,  // [2048][512] bf16
    unsigned short* __restrict__ HsAll) {     // [32][256][512] bf16; slot0 = h0
  __shared__ unsigned short hsh[32 * 512];    // 32 KB, XOR-swizzled chunks
  __shared__ float gsh[4][32 * 32];           // 16 KB
  const int tid = threadIdx.x;
  const int w = tid >> 6, l = tid & 63;
  const int gb = blockIdx.x & 7;              // batch group 0..7 (XCD-local heuristic)
  const int b0 = gb << 5;
  const int n0 = (blockIdx.x >> 3) << 5;      // col tile 0..15
  const int lr = l & 15;
  const int lk = (l >> 4) << 3;

  // ---- preload Whh fragments for this block's tile (gate group w, cols n0..n0+31)
  short8 bf0[16], bf1[16];
  {
    const unsigned short* wb0 = Whhb + (size_t)(w * 512 + n0 + lr) * 512 + lk;
    const unsigned short* wb1 = wb0 + (size_t)16 * 512;
#pragma unroll 16
    for (int ks = 0; ks < 16; ++ks) {
      bf0[ks] = *(const short8*)(wb0 + (ks << 5));
      bf1[ks] = *(const short8*)(wb1 + (ks << 5));
    }
  }
  float c_reg[4] = {0.f, 0.f, 0.f, 0.f};

  // cell ownership for the update phase: row br, 4 consecutive cols nc0
  const int br = tid >> 3;
  const int nc0 = (tid & 7) << 2;
  const size_t xg_base = ((size_t)(b0 + br) << 11) + n0 + nc0;

  for (int t = 0; t < NSTEP; ++t) {
    // ---- prefetch this step's Xg gate values into registers (cached loads;
    // latency hides under the sentinel-retry staging)
    const f32x4* xp = (const f32x4*)(Xg + (size_t)t * B_ * NG_ + xg_base);
    f32x4 xiv = xp[0];          // gate i  (+0)
    f32x4 xfv = xp[128];        // gate f  (+512 floats)
    f32x4 xgv = xp[256];        // gate g  (+1024)
    f32x4 xov = xp[384];        // gate o  (+1536)

    // ---- stage h_{t-1} rows b0..b0+31: retry until sentinel-free (data=flag)
    const unsigned short* h_in = HsAll + (size_t)t * B_ * H_;
    uint4 hreg[8];
    int ok;
    do {
#pragma unroll
      for (int j = 0; j < 8; ++j) {
        int row = (j << 2) + w;
        hreg[j] = load16_cc(h_in + (size_t)(b0 + row) * 512 + (l << 3));
      }
      asm volatile("s_waitcnt vmcnt(0)" ::: "memory");
      __builtin_amdgcn_sched_barrier(0);   // keep compares below the wait
      int val = 1;
#pragma unroll
      for (int j = 0; j < 8; ++j) {
        val &= (hreg[j].x != SENTU);
        val &= (hreg[j].y != SENTU);
        val &= (hreg[j].z != SENTU);
        val &= (hreg[j].w != SENTU);
      }
      ok = __syncthreads_and(val);
      if (!ok) __builtin_amdgcn_s_sleep(2);
    } while (!ok);

    // XOR-swizzled LDS write (chunk c of row lands at chunk c^(row&7))
#pragma unroll
    for (int j = 0; j < 8; ++j) {
      int row = (j << 2) + w;
      *(uint4*)(hsh + row * 512 + ((l ^ (row & 7)) << 3)) = hreg[j];
    }
    __syncthreads();

    // ---- h @ Whh^T for this gate group / col tile
    f32x4 acc[2][2] = {};
#pragma unroll
    for (int ks = 0; ks < 16; ++ks) {
      int kc = (ks << 2) + (l >> 4);
      short8 a0 = *(const short8*)(hsh + lr * 512 + ((kc ^ (lr & 7)) << 3));
      short8 a1 = *(const short8*)(hsh + (16 + lr) * 512 + ((kc ^ (lr & 7)) << 3));
      acc[0][0] = __builtin_amdgcn_mfma_f32_16x16x32_bf16(a0, bf0[ks], acc[0][0], 0, 0, 0);
      acc[0][1] = __builtin_amdgcn_mfma_f32_16x16x32_bf16(a0, bf1[ks], acc[0][1], 0, 0, 0);
      acc[1][0] = __builtin_amdgcn_mfma_f32_16x16x32_bf16(a1, bf0[ks], acc[1][0], 0, 0, 0);
      acc[1][1] = __builtin_amdgcn_mfma_f32_16x16x32_bf16(a1, bf1[ks], acc[1][1], 0, 0, 0);
    }

    // ---- gate tiles -> LDS (gate groups live in different waves)
    const int gr0 = (l >> 4) << 2;
#pragma unroll
    for (int m = 0; m < 2; ++m)
#pragma unroll
      for (int n = 0; n < 2; ++n)
#pragma unroll
        for (int r = 0; r < 4; ++r)
          gsh[w][(m * 16 + gr0 + r) * 32 + n * 16 + lr] = acc[m][n][r];
    __syncthreads();

    // ---- cell update + h_out (4 consecutive cells per thread, fast math)
    f32x4 giv = *(const f32x4*)&gsh[0][(br << 5) + nc0];
    f32x4 gfv = *(const f32x4*)&gsh[1][(br << 5) + nc0];
    f32x4 ggv = *(const f32x4*)&gsh[2][(br << 5) + nc0];
    f32x4 gov = *(const f32x4*)&gsh[3][(br << 5) + nc0];
    ushort4 hv;
    unsigned short* hvp = &hv.x;
#pragma unroll
    for (int j = 0; j < 4; ++j) {
      float is = fsig(giv[j] + xiv[j]);
      float fs = fsig(gfv[j] + xfv[j]);
      float os = fsig(gov[j] + xov[j]);
      float gt = ftanh_(ggv[j] + xgv[j]);
      float cn = fs * c_reg[j] + is * gt;
      c_reg[j] = cn;
      hvp[j] = f2bf(os * ftanh_(cn));
    }
    unsigned short* h_out = HsAll + (size_t)(t + 1) * B_ * H_;
    store8_cc(h_out + ((size_t)(b0 + br) << 9) + n0 + nc0,
              *reinterpret_cast<uint2*>(&hv));
    // no drain, no fence, no flag: consumers detect via the data itself.
  }
}

extern "C" void kernel_launch(void* const* d_in, const int* in_sizes, int n_in,
                              void* d_out, int out_size, void* d_ws, size_t ws_size,
                              hipStream_t stream) {
  const int*   caps   = (const int*)d_in[0];
  const float* latent = (const float*)d_in[1];
  const float* embed  = (const float*)d_in[2];
  const float* Wih    = (const float*)d_in[3];
  const float* Whh    = (const float*)d_in[4];
  const float* bih    = (const float*)d_in[5];
  const float* bhh    = (const float*)d_in[6];
  const float* Wlin   = (const float*)d_in[7];
  const float* blin   = (const float*)d_in[8];
  float* out = (float*)d_out;

  char* ws = (char*)d_ws;
  size_t off = 0;
  auto alloc = [&](size_t bytes) {
    void* p = ws + off;
    off = (off + bytes + 255) & ~(size_t)255;
    return p;
  };
  unsigned short* Xbf   = (unsigned short*)alloc((size_t)M_ * E_ * 2);
  unsigned short* Wihb  = (unsigned short*)alloc((size_t)NG_ * E_ * 2);
  unsigned short* Whhb  = (unsigned short*)alloc((size_t)NG_ * H_ * 2);
  unsigned short* Wlb   = (unsigned short*)alloc((size_t)VPAD_ * H_ * 2);
  float*          bias  = (float*)alloc((size_t)NG_ * 4);
  float*          Xg    = (float*)alloc((size_t)M_ * NG_ * 4);
  unsigned short* HsAll = (unsigned short*)alloc((size_t)(NSTEP + 1) * B_ * H_ * 2);
  (void)ws_size; (void)in_sizes; (void)n_in; (void)out_size;

  hipLaunchKernelGGL(k_prep, dim3(2048), dim3(256), 0, stream,
                     Wih, Whh, Wlin, bih, bhh, Wihb, Whhb, Wlb, bias);
  hipLaunchKernelGGL(k_gather, dim3(2048), dim3(256), 0, stream,
                     caps, embed, latent, Xbf, HsAll, out);
  // Xg = X @ Wih^T + bias   [7936 x 2048]  (normal stores: chain re-reads Xg)
  hipLaunchKernelGGL((gemm256<false>), dim3(NG_ / 256, M_ / 256), dim3(512), 0, stream,
                     Xbf, Wihb, bias, Xg, NG_, NG_);
  // persistent LSTM chain, sentinel-synced (cooperative launch only for
  // guaranteed co-residency of all 128 blocks)
  {
    const float* XgC = Xg;
    const unsigned short* WhhC = Whhb;
    unsigned short* HsC = HsAll;
    void* args[] = {(void*)&XgC, (void*)&WhhC, (void*)&HsC};
    hipLaunchCooperativeKernel((const void*)k_chain, dim3(128), dim3(256),
                               args, 0, stream);
  }
  // logits = Hs @ Wlin^T + b_lin -> out rows starting at B_*V_ (NT stores)
  hipLaunchKernelGGL((gemm256<true>), dim3(VPAD_ / 256, M_ / 256), dim3(512), 0, stream,
                     HsAll + (size_t)B_ * H_, Wlb, blin, out + (size_t)B_ * V_, V_, V_);
}